// Round 6
// baseline (272.801 us; speedup 1.0000x reference)
//
#include <hip/hip_runtime.h>
#include <math.h>

#define C 4096
#define NF4 (C / 4)   // float4 elements per row (1024)

// dot(float4,float4)
__device__ __forceinline__ float dot4(float4 a, float4 b) {
    return a.x * b.x + a.y * b.y + a.z * b.z + a.w * b.w;
}

// ---------------------------------------------------------------------------
// Kernel 1: fused [mix] + [kw@xk, vw@xv, rw@xr] + [wkv] + state outputs.
// One wave per row (all three matrices, sequential phases). NEW vs R5:
//  (a) per-(row,matrix) ROTATED column start at 1 KB chunk granularity —
//      breaks the chip-wide address convoy (all streams previously walked
//      columns in lockstep at identical 16 KB phase -> channel collapse);
//  (b) 8-deep load pipeline (preload 8 chunks, issue next 8, then consume).
// ---------------------------------------------------------------------------
__global__ __launch_bounds__(256) void gemv_kvr_wkv_kernel(
    const float* __restrict__ kw, const float* __restrict__ vw, const float* __restrict__ rw,
    const float* __restrict__ x, const float* __restrict__ state,
    const float* __restrict__ tmk, const float* __restrict__ tmv, const float* __restrict__ tmr,
    const float* __restrict__ aa, const float* __restrict__ bb, const float* __restrict__ pp,
    const float* __restrict__ time_first, const float* __restrict__ time_decay,
    float* __restrict__ rwkv, float* __restrict__ new_state,
    float* __restrict__ out_sa, float* __restrict__ out_sb, float* __restrict__ out_sp)
{
    __shared__ float4 xs[NF4];   // 16 KiB: mixed vector for the current phase

    const int t    = threadIdx.x;
    const int wave = t >> 6;
    const int lane = t & 63;
    const int row  = blockIdx.x * 4 + wave;

    const float4* x4 = (const float4*)x;
    const float4* s4 = (const float4*)state;

    float kk_r = 0.f, vv_r = 0.f, rr_r = 0.f;

#pragma unroll
    for (int m = 0; m < 3; ++m) {
        const float* W  = (m == 0) ? kw  : (m == 1) ? vw  : rw;
        const float* Tm = (m == 0) ? tmk : (m == 1) ? tmv : tmr;

        __syncthreads();   // previous phase's xs readers done
        const float4* t4 = (const float4*)Tm;
#pragma unroll
        for (int j = 0; j < 4; ++j) {
            int i = j * 256 + t;
            float4 xi = x4[i], si = s4[i], ti = t4[i];
            float4 r;
            r.x = si.x + ti.x * (xi.x - si.x);
            r.y = si.y + ti.y * (xi.y - si.y);
            r.z = si.z + ti.z * (xi.z - si.z);
            r.w = si.w + ti.w * (xi.w - si.w);
            xs[i] = r;
        }
        __syncthreads();

        const float4* Wp = (const float4*)(W + (size_t)row * C);
        // Per-(row, matrix) rotation of the chunk walk (chunk = 64 float4 = 1 KB).
        const int c0 = (row * 5 + m * 3) & 15;
#define CADDR(u) ((((c0 + (u)) & 15) << 6) + lane)

        // Preload 8 chunks, then issue the other 8, then consume.
        float4 w0 = Wp[CADDR(0)], w1 = Wp[CADDR(1)], w2 = Wp[CADDR(2)], w3 = Wp[CADDR(3)];
        float4 w4 = Wp[CADDR(4)], w5 = Wp[CADDR(5)], w6 = Wp[CADDR(6)], w7 = Wp[CADDR(7)];
        float4 n0 = Wp[CADDR(8)],  n1 = Wp[CADDR(9)],  n2 = Wp[CADDR(10)], n3 = Wp[CADDR(11)];
        float4 n4 = Wp[CADDR(12)], n5 = Wp[CADDR(13)], n6 = Wp[CADDR(14)], n7 = Wp[CADDR(15)];

        float a0 = 0.f, a1 = 0.f, a2 = 0.f, a3 = 0.f;
        a0 += dot4(w0, xs[CADDR(0)]);
        a1 += dot4(w1, xs[CADDR(1)]);
        a2 += dot4(w2, xs[CADDR(2)]);
        a3 += dot4(w3, xs[CADDR(3)]);
        a0 += dot4(w4, xs[CADDR(4)]);
        a1 += dot4(w5, xs[CADDR(5)]);
        a2 += dot4(w6, xs[CADDR(6)]);
        a3 += dot4(w7, xs[CADDR(7)]);
        a0 += dot4(n0, xs[CADDR(8)]);
        a1 += dot4(n1, xs[CADDR(9)]);
        a2 += dot4(n2, xs[CADDR(10)]);
        a3 += dot4(n3, xs[CADDR(11)]);
        a0 += dot4(n4, xs[CADDR(12)]);
        a1 += dot4(n5, xs[CADDR(13)]);
        a2 += dot4(n6, xs[CADDR(14)]);
        a3 += dot4(n7, xs[CADDR(15)]);
#undef CADDR

        float s = (a0 + a1) + (a2 + a3);
        s += __shfl_down(s, 32, 64);
        s += __shfl_down(s, 16, 64);
        s += __shfl_down(s,  8, 64);
        s += __shfl_down(s,  4, 64);
        s += __shfl_down(s,  2, 64);
        s += __shfl_down(s,  1, 64);
        if (m == 0) kk_r = s; else if (m == 1) vv_r = s; else rr_r = s;
    }

    if (lane == 0) {
        const int i = row;
        float kk = kk_r, vv = vv_r, rr = rr_r;
        float a_ = aa[i], b_ = bb[i], p_ = pp[i];

        float ww = time_first[i] + kk;
        float p  = fmaxf(p_, ww);
        float e1 = expf(p_ - p);
        float e2 = expf(ww - p);
        float a  = e1 * a_ + e2 * vv;
        float b  = e1 * b_ + e2;

        float ww2 = p_ + time_decay[i];
        float p2  = fmaxf(ww2, kk);
        float e1b = expf(ww2 - p2);
        float e2b = expf(kk - p2);
        out_sa[i] = e1b * a_ + e2b * vv;
        out_sb[i] = e1b * b_ + e2b;
        out_sp[i] = p2;

        new_state[i] = x[i];

        float r = 1.0f / (1.0f + expf(-rr));
        rwkv[i] = r * (a / b);
    }
}

// ---------------------------------------------------------------------------
// Kernel 2: out = ow @ rwkv. Same rotated, 8-deep pipelined GEMV core.
// ---------------------------------------------------------------------------
__global__ __launch_bounds__(256) void gemv_ow_kernel(const float* __restrict__ W,
                                                      const float* __restrict__ xin,
                                                      float* __restrict__ out)
{
    __shared__ float4 xs[NF4];

    const int t    = threadIdx.x;
    const int wave = t >> 6;
    const int lane = t & 63;
    const int row  = blockIdx.x * 4 + wave;

    const float4* x4 = (const float4*)xin;
#pragma unroll
    for (int j = 0; j < 4; ++j) {
        int i = j * 256 + t;
        xs[i] = x4[i];
    }
    __syncthreads();

    const float4* Wp = (const float4*)(W + (size_t)row * C);
    const int c0 = (row * 5 + 9) & 15;
#define CADDR(u) ((((c0 + (u)) & 15) << 6) + lane)

    float4 w0 = Wp[CADDR(0)], w1 = Wp[CADDR(1)], w2 = Wp[CADDR(2)], w3 = Wp[CADDR(3)];
    float4 w4 = Wp[CADDR(4)], w5 = Wp[CADDR(5)], w6 = Wp[CADDR(6)], w7 = Wp[CADDR(7)];
    float4 n0 = Wp[CADDR(8)],  n1 = Wp[CADDR(9)],  n2 = Wp[CADDR(10)], n3 = Wp[CADDR(11)];
    float4 n4 = Wp[CADDR(12)], n5 = Wp[CADDR(13)], n6 = Wp[CADDR(14)], n7 = Wp[CADDR(15)];

    float a0 = 0.f, a1 = 0.f, a2 = 0.f, a3 = 0.f;
    a0 += dot4(w0, xs[CADDR(0)]);
    a1 += dot4(w1, xs[CADDR(1)]);
    a2 += dot4(w2, xs[CADDR(2)]);
    a3 += dot4(w3, xs[CADDR(3)]);
    a0 += dot4(w4, xs[CADDR(4)]);
    a1 += dot4(w5, xs[CADDR(5)]);
    a2 += dot4(w6, xs[CADDR(6)]);
    a3 += dot4(w7, xs[CADDR(7)]);
    a0 += dot4(n0, xs[CADDR(8)]);
    a1 += dot4(n1, xs[CADDR(9)]);
    a2 += dot4(n2, xs[CADDR(10)]);
    a3 += dot4(n3, xs[CADDR(11)]);
    a0 += dot4(n4, xs[CADDR(12)]);
    a1 += dot4(n5, xs[CADDR(13)]);
    a2 += dot4(n6, xs[CADDR(14)]);
    a3 += dot4(n7, xs[CADDR(15)]);
#undef CADDR

    float s = (a0 + a1) + (a2 + a3);
    s += __shfl_down(s, 32, 64);
    s += __shfl_down(s, 16, 64);
    s += __shfl_down(s,  8, 64);
    s += __shfl_down(s,  4, 64);
    s += __shfl_down(s,  2, 64);
    s += __shfl_down(s,  1, 64);
    if (lane == 0) out[row] = s;
}

// ---------------------------------------------------------------------------
extern "C" void kernel_launch(void* const* d_in, const int* in_sizes, int n_in,
                              void* d_out, int out_size, void* d_ws, size_t ws_size,
                              hipStream_t stream) {
    const float* x          = (const float*)d_in[0];
    const float* state      = (const float*)d_in[1];
    const float* state_a    = (const float*)d_in[2];
    const float* state_b    = (const float*)d_in[3];
    const float* state_p    = (const float*)d_in[4];
    const float* tmk        = (const float*)d_in[5];
    const float* tmv        = (const float*)d_in[6];
    const float* tmr        = (const float*)d_in[7];
    const float* time_first = (const float*)d_in[8];
    const float* time_decay = (const float*)d_in[9];
    const float* kw         = (const float*)d_in[10];
    const float* vw         = (const float*)d_in[11];
    const float* rw         = (const float*)d_in[12];
    const float* ow         = (const float*)d_in[13];

    float* out       = (float*)d_out;        // [0:C)
    float* new_state = out + C;              // [C:2C)
    float* new_sa    = out + 2 * C;          // [2C:3C)
    float* new_sb    = out + 3 * C;          // [3C:4C)
    float* new_sp    = out + 4 * C;          // [4C:5C)

    float* rwkv = (float*)d_ws;              // [0:C) of workspace

    gemv_kvr_wkv_kernel<<<C / 4, 256, 0, stream>>>(
        kw, vw, rw, x, state, tmk, tmv, tmr,
        state_a, state_b, state_p, time_first, time_decay,
        rwkv, new_state, new_sa, new_sb, new_sp);

    gemv_ow_kernel<<<C / 4, 256, 0, stream>>>(ow, rwkv, out);
}